// Round 10
// baseline (202.336 us; speedup 1.0000x reference)
//
#include <hip/hip_runtime.h>
#include <math.h>

// DeformAtten2D: B=4, H=W=C=128.
// R17: R16 post-mortem — fused3 40.4->53.5us after q-phase removal: the q
// GEMM had been the overlap work covering the gather drain; removing it
// exposed ~13us of naked scattered-load latency at barrier B3. Fix: per-wave
// dataflow. k&v GEMM repartitioned to per-wave row ownership (wave w owns
// A-rows w*32..+31, all 128 planes, acc[2][8]); wave w gathers exactly its
// own px rows -> gather->GEMM dependency is wave-local (lgkmcnt, NO barrier);
// waves drift so one wave's MFMA covers another's gather loads (m114
// mechanism). vw GEMM same treatment. 7->6 barriers. Weight B-frag loads
// double (L2-hot, acceptable). Accumulation order per output bit-identical.
// k_off (R16, q fused), k_attn3 (R15), k_wprep unchanged.
#define IMG 16384   // 128*128

typedef short short4v __attribute__((ext_vector_type(4)));
typedef short short8  __attribute__((ext_vector_type(8)));
typedef float floatx4 __attribute__((ext_vector_type(4)));

__device__ __forceinline__ float4 ld4(const float* p) {
    return *reinterpret_cast<const float4*>(p);
}
__device__ __forceinline__ short f2bf(float f) {
    union { float f; unsigned u; } v; v.f = f;
    unsigned r = v.u + 0x7fffu + ((v.u >> 16) & 1u);   // RNE
    return (short)(r >> 16);
}
__device__ __forceinline__ float bf2f(short s) {
    union { unsigned u; float f; } v;
    v.u = ((unsigned)(unsigned short)s) << 16;
    return v.f;
}

// ---------------------------------------------------------------------------
// Kernel 1: blocks 0..49: o50=(t,tap) weight folding (W2, cst, b_eff) +
//           split-bf16 W2 (w2h/w2l). blocks 50..81: [Wq|Wk|Wv|Wo] -> bf16.
// ---------------------------------------------------------------------------
__launch_bounds__(256)
__global__ void k_wprep(const float* __restrict__ Wc1, const float* __restrict__ Wc2,
                        const float* __restrict__ bc1, const float* __restrict__ Wq,
                        const float* __restrict__ bq, const float* __restrict__ Wk,
                        const float* __restrict__ Wv, const float* __restrict__ Wo,
                        float* __restrict__ W2, float* __restrict__ cst,
                        float* __restrict__ b_eff, short* __restrict__ wbf,
                        short* __restrict__ w2h, short* __restrict__ w2l) {
    const int t = threadIdx.x;
    if (blockIdx.x >= 50) {                  // weight bf16 conversion
        if (blockIdx.x == 50) {              // zero-pad W2 split rows 50..63
            for (int i = t; i < 14 * 128; i += 256) {
                w2h[6400 + i] = 0;
                w2l[6400 + i] = 0;
            }
        }
        int i = (blockIdx.x - 50) * 256 + t;  // < 8192
        int base = i * 8;
        int sel = base >> 14, off = base & 16383;
        const float* s = (sel == 0) ? Wq : (sel == 1) ? Wk : (sel == 2) ? Wv : Wo;
        float4 a = ld4(s + off), b = ld4(s + off + 4);
        short8 o;
        o[0] = f2bf(a.x); o[1] = f2bf(a.y); o[2] = f2bf(a.z); o[3] = f2bf(a.w);
        o[4] = f2bf(b.x); o[5] = f2bf(b.y); o[6] = f2bf(b.z); o[7] = f2bf(b.w);
        *reinterpret_cast<short8*>(wbf + base) = o;
        return;
    }
    __shared__ float U[128];
    __shared__ float red[256];
    __shared__ float wc2[128];
    __shared__ float bql[128];
    const int tt = blockIdx.x;               // 0..49
    const int tch = tt / 25, tap = tt % 25;
    if (t < 128) { wc2[t] = Wc2[tch * 128 + t]; bql[t] = bq[t]; }
    __syncthreads();
    const int c = t & 127, half = t >> 7;
    float p = 0.f;
    for (int o = half * 64; o < half * 64 + 64; ++o)
        p += wc2[o] * Wc1[(o * 128 + c) * 25 + tap];
    red[half * 128 + c] = p;
    __syncthreads();
    if (t < 128) U[t] = red[t] + red[128 + t];
    __syncthreads();
    float p2 = 0.f;
    for (int cc = half * 64; cc < half * 64 + 64; ++cc)
        p2 += U[cc] * Wq[cc * 128 + c];
    red[half * 128 + c] = p2;
    __syncthreads();
    if (t < 128) {
        float vv = red[t] + red[128 + t];
        W2[tt * 128 + t] = vv;
        short hh = f2bf(vv);
        w2h[tt * 128 + t] = hh;
        w2l[tt * 128 + t] = f2bf(vv - bf2f(hh));
    }
    if (t < 128) red[t] = U[t] * bql[t];
    __syncthreads();
    if (t == 0) {
        float s = 0.f;
        for (int j = 0; j < 128; ++j) s += red[j];
        cst[tt] = s;
    }
    if (tap == 0) {
        __syncthreads();
        if (t < 128) red[t] = wc2[t] * bc1[t];
        __syncthreads();
        if (t == 0) {
            float s = 0.f;
            for (int j = 0; j < 128; ++j) s += red[j];
            b_eff[tch] = s;
        }
    }
}

// ---------------------------------------------------------------------------
// Kernel 2 (R16): P[b][o50][pix] = W2·x + cst (split-bf16 hh+hl+lh) AND
// q[b][o][pix] = x·Wq^T + bq (bf16, bit-identical to the old fused3 q GEMM).
// 512 blocks; block = one (b,h) row of 128 px.
// ---------------------------------------------------------------------------
__launch_bounds__(256, 2)
__global__ void k_off(const float* __restrict__ x, const short* __restrict__ w2h,
                      const short* __restrict__ w2l, const float* __restrict__ cst,
                      const float* __restrict__ bq, const short* __restrict__ wbf,
                      float* __restrict__ P, short* __restrict__ x_bf,
                      short* __restrict__ q_bf) {
    __shared__ __align__(16) char smem[34816];
    float* stageF = (float*)smem;                 // 64x132 fp32 (P) = 33792 B
    short* stageS = (short*)smem;                 // 128x136 bf16 (q) = 34816 B
    const int t = threadIdx.x;
    const int w = t >> 6, l = t & 63, l15 = l & 15, quad = l >> 4;
    const int p0 = blockIdx.x * 128;
    const int b = p0 >> 14, pix0 = p0 & (IMG - 1);
    const int h = pix0 >> 7;                      // image row of this block

    floatx4 accP[2][4];
    floatx4 accQ[2][8];
#pragma unroll
    for (int im = 0; im < 2; ++im) {
#pragma unroll
        for (int in = 0; in < 4; ++in) accP[im][in] = (floatx4){0.f, 0.f, 0.f, 0.f};
#pragma unroll
        for (int in = 0; in < 8; ++in) accQ[im][in] = (floatx4){0.f, 0.f, 0.f, 0.f};
    }

    const float* xb = x + (size_t)p0 * 128;
    short* xbb = x_bf + (size_t)p0 * 128;

#pragma unroll
    for (int kc = 0; kc < 128; kc += 32) {
        short8 ah[2], al[2];
#pragma unroll
        for (int im = 0; im < 2; ++im) {
            int row = w * 32 + im * 16 + l15;
            const float* src = xb + row * 128 + kc + quad * 8;
            float4 f0 = ld4(src), f1 = ld4(src + 4);
            float fv[8] = {f0.x, f0.y, f0.z, f0.w, f1.x, f1.y, f1.z, f1.w};
            short8 h8, l8;
#pragma unroll
            for (int r = 0; r < 8; ++r) {
                short hh = f2bf(fv[r]);
                h8[r] = hh;
                l8[r] = f2bf(fv[r] - bf2f(hh));
            }
            ah[im] = h8; al[im] = l8;
            *reinterpret_cast<short8*>(xbb + row * 128 + kc + quad * 8) = h8;
        }
        short8 bh[4], bl[4], bqf[8];
#pragma unroll
        for (int in = 0; in < 4; ++in) {
            int o = in * 16 + l15;
            bh[in] = *reinterpret_cast<const short8*>(w2h + o * 128 + kc + quad * 8);
            bl[in] = *reinterpret_cast<const short8*>(w2l + o * 128 + kc + quad * 8);
        }
#pragma unroll
        for (int in = 0; in < 8; ++in)
            bqf[in] = *reinterpret_cast<const short8*>(
                wbf + (in * 16 + l15) * 128 + kc + quad * 8);
#pragma unroll
        for (int im = 0; im < 2; ++im) {
#pragma unroll
            for (int in = 0; in < 4; ++in) {
                accP[im][in] = __builtin_amdgcn_mfma_f32_16x16x32_bf16(
                    ah[im], bh[in], accP[im][in], 0, 0, 0);
                accP[im][in] = __builtin_amdgcn_mfma_f32_16x16x32_bf16(
                    ah[im], bl[in], accP[im][in], 0, 0, 0);
                accP[im][in] = __builtin_amdgcn_mfma_f32_16x16x32_bf16(
                    al[im], bh[in], accP[im][in], 0, 0, 0);
            }
#pragma unroll
            for (int in = 0; in < 8; ++in)
                accQ[im][in] = __builtin_amdgcn_mfma_f32_16x16x32_bf16(
                    ah[im], bqf[in], accQ[im][in], 0, 0, 0);
        }
    }
    // ---- stage P tile (o 0..63 x px 0..127) then coalesced write of o<50 ----
#pragma unroll
    for (int im = 0; im < 2; ++im)
#pragma unroll
        for (int in = 0; in < 4; ++in) {
            int o = in * 16 + l15;
            int row0 = w * 32 + im * 16 + quad * 4;
            *reinterpret_cast<float4*>(&stageF[o * 132 + row0]) =
                make_float4(accP[im][in][0], accP[im][in][1],
                            accP[im][in][2], accP[im][in][3]);
        }
    __syncthreads();
    for (int id = t; id < 50 * 32; id += 256) {
        int o = id >> 5, px4 = (id & 31) * 4;
        float c = cst[o];
        float4 v = *reinterpret_cast<float4*>(&stageF[o * 132 + px4]);
        v.x += c; v.y += c; v.z += c; v.w += c;
        *reinterpret_cast<float4*>(P + ((size_t)(b * 50 + o)) * IMG + pix0 + px4) = v;
    }
    __syncthreads();                              // stageF reads done
    // ---- stage q bf16 (o 0..127 x px 0..127) ----
#pragma unroll
    for (int in = 0; in < 8; ++in) {
        int o = in * 16 + l15;
        float bb = bq[o];
#pragma unroll
        for (int im = 0; im < 2; ++im) {
            int row0 = w * 32 + im * 16 + quad * 4;
            short4v s = {f2bf(accQ[im][in][0] + bb), f2bf(accQ[im][in][1] + bb),
                         f2bf(accQ[im][in][2] + bb), f2bf(accQ[im][in][3] + bb)};
            *reinterpret_cast<short4v*>(&stageS[o * 136 + row0]) = s;
        }
    }
    __syncthreads();
    // coalesced q write
    for (int id = t; id < 2048; id += 256) {
        int o = id >> 4, seg = id & 15;
        *reinterpret_cast<short8*>(
            q_bf + ((size_t)(b * 128 + o)) * IMG + h * 128 + seg * 8)
            = *reinterpret_cast<const short8*>(&stageS[o * 136 + seg * 8]);
    }
}

// ---------------------------------------------------------------------------
// Kernel 3 (R17): FUSED per (b,h) row, 256 threads, 6 barriers, per-wave
// dataflow for the gather->GEMM path.
//   A: P rows (branch-free clamped loads) -> zero-halo conv -> tanh*5 (LDS)
//   B: per-wave gather: wave w gathers px w*32..w*32+31 -> xsT (NO barrier;
//      wave-local lgkmcnt dependency)
//   C: per-wave k&v GEMM (wave w: A-rows w*32..+31, all 128 planes,
//      acc[2][8]); B4; stage k->stg, v->xsT; B5; k write; per-wave vw GEMM
//      (Wo A-rows w*32..+31); B6; stage vw->stg; B7; vw write.
// LDS: stg/rowsP 34816 + xsT 34816 + offs 1024 = 70656 B (2 blocks/CU).
// ---------------------------------------------------------------------------
__launch_bounds__(256, 2)
__global__ void k_fused3(const float* __restrict__ P, const float* __restrict__ b_eff,
                         const short* __restrict__ x_bf, const short* __restrict__ wbf,
                         const float* __restrict__ bk, const float* __restrict__ bv,
                         const float* __restrict__ rel,
                         short* __restrict__ k_bf, short* __restrict__ v_bf) {
    __shared__ __align__(16) char smem[70656];
    float* rowsP  = (float*)smem;                // 27200 B (phase A only)
    short* stg    = (short*)smem;                // 34816 B stage (aliases rowsP)
    short* xsT    = (short*)(smem + 34816);      // 34816 B
    float* offs_l = (float*)(smem + 69632);      // 1024 B

    const int t = threadIdx.x;
    const int w = t >> 6, l = t & 63, l15 = l & 15, quad = l >> 4;
    const int bh = blockIdx.x;
    const int b = bh >> 7, h = bh & 127;

    // ---- Phase A: P rows (5-row halo), branch-free clamped loads ----
    for (int id = t; id < 1600; id += 256) {
        int o = id >> 5, q4 = (id & 31) * 4;
        int di = (o % 25) / 5;
        int r = h + di - 2;
        int rc = min(max(r, 0), 127);
        float4 v = ld4(P + ((size_t)(b * 50 + o)) * IMG + rc * 128 + q4);
        float m = (r >= 0 && r < 128) ? 1.f : 0.f;
        v.x *= m; v.y *= m; v.z *= m; v.w *= m;
        *reinterpret_cast<float4*>(&rowsP[o * 136 + 4 + q4]) = v;
    }
    // zero the 4-col halos (cols 0..3 and 132..135) of each of 50 planes
    for (int id = t; id < 400; id += 256) {
        int o = id >> 3, c = id & 7;
        rowsP[o * 136 + (c < 4 ? c : 128 + c)] = 0.f;
    }
    __syncthreads();                             // B1
    {
        int wp = t & 127, tc = t >> 7;
        float acc = 0.f;
#pragma unroll
        for (int di = 0; di < 5; ++di)
#pragma unroll
            for (int dj = 0; dj < 5; ++dj)
                acc += rowsP[(tc * 25 + di * 5 + dj) * 136 + wp + dj + 2];
        offs_l[tc * 128 + wp] = tanhf(acc + b_eff[tc]) * 5.0f;
    }
    __syncthreads();                             // B2: offs ready, rowsP dead

    // ---- Phase B: per-wave branch-free gather -> xsT (NO barrier) ----
    {
        const short* xbase = x_bf + (size_t)b * IMG * 128;
#pragma unroll
        for (int it = 0; it < 8; ++it) {
            int local = l + it * 64;             // 0..511 within wave
            int px = w * 32 + (local >> 4);      // wave's own rows
            int c8 = local & 15;
            float ox = offs_l[px];
            float oy = offs_l[128 + px];
            float xg = ((float)px + ox) * (128.0f / 127.0f) - 0.5f;
            float yg = ((float)h  + oy) * (128.0f / 127.0f) - 0.5f;
            float x0f = floorf(xg), y0f = floorf(yg);
            float fx = xg - x0f, fy = yg - y0f;
            int x0 = (int)x0f, y0 = (int)y0f;
            float s[8];
#pragma unroll
            for (int r = 0; r < 8; ++r) s[r] = 0.f;
#pragma unroll
            for (int tap = 0; tap < 4; ++tap) {
                int xi = x0 + (tap & 1), yi = y0 + (tap >> 1);
                float wgt = ((tap & 1) ? fx : 1.f - fx) * ((tap >> 1) ? fy : 1.f - fy);
                wgt = (xi >= 0 && xi < 128 && yi >= 0 && yi < 128) ? wgt : 0.f;
                int xc = min(max(xi, 0), 127), yc = min(max(yi, 0), 127);
                short8 v = *reinterpret_cast<const short8*>(
                    xbase + ((size_t)(yc * 128 + xc)) * 128 + c8 * 8);
#pragma unroll
                for (int r = 0; r < 8; ++r) s[r] = fmaf(wgt, bf2f(v[r]), s[r]);
            }
            short8 o;
#pragma unroll
            for (int r = 0; r < 8; ++r) o[r] = f2bf(s[r]);
            *reinterpret_cast<short8*>(&xsT[px * 136 + c8 * 8]) = o;
        }
    }

    // ---- per-wave fused k & v GEMMs (A-rows = wave's gathered rows) ----
    {
        floatx4 ak[2][8], av[2][8];
#pragma unroll
        for (int im = 0; im < 2; ++im)
#pragma unroll
            for (int in = 0; in < 8; ++in) {
                ak[im][in] = (floatx4){0.f, 0.f, 0.f, 0.f};
                av[im][in] = (floatx4){0.f, 0.f, 0.f, 0.f};
            }
#pragma unroll
        for (int kc = 0; kc < 128; kc += 32) {
            short8 af[2], bk_[8], bv_[8];
#pragma unroll
            for (int im = 0; im < 2; ++im)
                af[im] = *reinterpret_cast<const short8*>(
                    &xsT[(w * 32 + im * 16 + l15) * 136 + kc + quad * 8]);
#pragma unroll
            for (int in = 0; in < 8; ++in) {
                bk_[in] = *reinterpret_cast<const short8*>(
                    wbf + 16384 + (in * 16 + l15) * 128 + kc + quad * 8);
                bv_[in] = *reinterpret_cast<const short8*>(
                    wbf + 32768 + (in * 16 + l15) * 128 + kc + quad * 8);
            }
#pragma unroll
            for (int im = 0; im < 2; ++im)
#pragma unroll
                for (int in = 0; in < 8; ++in) {
                    ak[im][in] = __builtin_amdgcn_mfma_f32_16x16x32_bf16(
                        af[im], bk_[in], ak[im][in], 0, 0, 0);
                    av[im][in] = __builtin_amdgcn_mfma_f32_16x16x32_bf16(
                        af[im], bv_[in], av[im][in], 0, 0, 0);
                }
        }
        __syncthreads();                         // B4: all waves' xsT reads done
        // stage k -> stg, biased v -> xsT (per-wave column range)
#pragma unroll
        for (int in = 0; in < 8; ++in) {
            int o = in * 16 + l15;
            float bbk = bk[o];
            float bbv = bv[o] + rel[o * 128 + h];
#pragma unroll
            for (int im = 0; im < 2; ++im) {
                int row0 = w * 32 + im * 16 + quad * 4;
                short4v sk = {f2bf(ak[im][in][0] + bbk), f2bf(ak[im][in][1] + bbk),
                              f2bf(ak[im][in][2] + bbk), f2bf(ak[im][in][3] + bbk)};
                short4v sv = {f2bf(av[im][in][0] + bbv), f2bf(av[im][in][1] + bbv),
                              f2bf(av[im][in][2] + bbv), f2bf(av[im][in][3] + bbv)};
                *reinterpret_cast<short4v*>(&stg[o * 136 + row0]) = sk;
                *reinterpret_cast<short4v*>(&xsT[o * 136 + row0]) = sv;
            }
        }
    }
    __syncthreads();                             // B5
    // coalesced k write
    for (int id = t; id < 2048; id += 256) {
        int o = id >> 4, seg = id & 15;
        *reinterpret_cast<short8*>(
            k_bf + ((size_t)(b * 128 + o)) * IMG + h * 128 + seg * 8)
            = *reinterpret_cast<const short8*>(&stg[o * 136 + seg * 8]);
    }

    // ---- per-wave vw = v·Wo^T GEMM: D[o'][plane], o' rows w*32..+31 ----
    {
        const short* WoB = wbf + 49152;
        floatx4 aw[2][8];
#pragma unroll
        for (int im = 0; im < 2; ++im)
#pragma unroll
            for (int in = 0; in < 8; ++in)
                aw[im][in] = (floatx4){0.f, 0.f, 0.f, 0.f};
#pragma unroll
        for (int kc = 0; kc < 128; kc += 32) {
            short8 af[2], bf_[8];
#pragma unroll
            for (int im = 0; im < 2; ++im)
                af[im] = *reinterpret_cast<const short8*>(
                    WoB + (w * 32 + im * 16 + l15) * 128 + kc + quad * 8);
#pragma unroll
            for (int in = 0; in < 8; ++in)
                bf_[in] = *reinterpret_cast<const short8*>(
                    &xsT[(in * 16 + l15) * 136 + kc + quad * 8]);
#pragma unroll
            for (int im = 0; im < 2; ++im)
#pragma unroll
                for (int in = 0; in < 8; ++in)
                    aw[im][in] = __builtin_amdgcn_mfma_f32_16x16x32_bf16(
                        af[im], bf_[in], aw[im][in], 0, 0, 0);
        }
        __syncthreads();                         // B6: k-write stg reads + xsT reads done
        // stage vw: stg[plane][o' cols w*32..+31]
#pragma unroll
        for (int in = 0; in < 8; ++in) {
            int plane = in * 16 + l15;
#pragma unroll
            for (int im = 0; im < 2; ++im) {
                int row0 = w * 32 + im * 16 + quad * 4;    // o' base
                short4v s = {f2bf(aw[im][in][0]), f2bf(aw[im][in][1]),
                             f2bf(aw[im][in][2]), f2bf(aw[im][in][3])};
                *reinterpret_cast<short4v*>(&stg[plane * 136 + row0]) = s;
            }
        }
    }
    __syncthreads();                             // B7
    // coalesced vw write into v_bf
    for (int id = t; id < 2048; id += 256) {
        int o = id >> 4, seg = id & 15;
        *reinterpret_cast<short8*>(
            v_bf + ((size_t)(b * 128 + o)) * IMG + h * 128 + seg * 8)
            = *reinterpret_cast<const short8*>(&stg[o * 136 + seg * 8]);
    }
}

// ---------------------------------------------------------------------------
// Kernel 4 (R15): MFMA attention, 2 phases. Phase 1: S=q·kT + softmax.
// Phase 2: Y = P·vw + bo (Wo pre-folded into vw by k_fused3). b64-packed
// vw->vT transpose; Y staged fp32 in LDS -> coalesced float4 stores.
// LDS: Pb 34816 + vT 34816 + redm 1024 + reds 1024 = 71680 B (2 blocks/CU).
// ---------------------------------------------------------------------------
__launch_bounds__(256, 2)
__global__ void k_attn3(const short* __restrict__ q_bf, const short* __restrict__ k_bf,
                        const short* __restrict__ v_bf,
                        const float* __restrict__ bo, float* __restrict__ outp) {
    __shared__ __align__(16) char smem[71680];
    short* Pb   = (short*)smem;                  // 34816 B: P bf16
    short* vT   = (short*)(smem + 34816);        // 34816 B: vw^T swizzled
    float* Ystg = (float*)smem;                  // 128x132 fp32 = 67584 B (epilogue)
    float* redm = (float*)(smem + 69632);        // 512 B x2
    float* reds = (float*)(smem + 70656);        // 512 B x2

    const int t = threadIdx.x;
    const int w = t >> 6, l = t & 63, l15 = l & 15, quad = l >> 4;
    const int mh = w >> 1, nh = w & 1;
    const size_t hb = (size_t)blockIdx.x * IMG;
    const short* qp = q_bf + hb;
    const short* kp = k_bf + hb;
    const short* vp = v_bf + hb;

    // ---- vw -> vT transpose (b64 writes, swizzled): 512 items, 2/thread ----
    for (int id = t; id < 512; id += 256) {
        int j4 = id >> 4, seg = id & 15;             // j-block of 4, d-block of 8
        const short* src = vp + (j4 * 4) * 128 + seg * 8;
        short8 v0 = *reinterpret_cast<const short8*>(src);
        short8 v1 = *reinterpret_cast<const short8*>(src + 128);
        short8 v2 = *reinterpret_cast<const short8*>(src + 256);
        short8 v3 = *reinterpret_cast<const short8*>(src + 384);
        int phys = (((j4 >> 1) ^ seg) & 15) * 8 + (j4 & 1) * 4;
#pragma unroll
        for (int r = 0; r < 8; ++r) {
            short4v wv = {v0[r], v1[r], v2[r], v3[r]};
            *reinterpret_cast<short4v*>(&vT[(seg * 8 + r) * 136 + phys]) = wv;
        }
    }

    floatx4 acc[4][4];
#pragma unroll
    for (int im = 0; im < 4; ++im)
#pragma unroll
        for (int in = 0; in < 4; ++in)
            acc[im][in] = (floatx4){0.f, 0.f, 0.f, 0.f};

    // ---- Phase 1: S = q·kT (direct-global frags) ----
#pragma unroll
    for (int kc = 0; kc < 128; kc += 32) {
        short8 af[4], bf_[4];
#pragma unroll
        for (int im = 0; im < 4; ++im)
            af[im] = *reinterpret_cast<const short8*>(
                qp + (mh * 64 + im * 16 + l15) * 128 + kc + quad * 8);
#pragma unroll
        for (int in = 0; in < 4; ++in)
            bf_[in] = *reinterpret_cast<const short8*>(
                kp + (nh * 64 + in * 16 + l15) * 128 + kc + quad * 8);
#pragma unroll
        for (int im = 0; im < 4; ++im)
#pragma unroll
            for (int in = 0; in < 4; ++in)
                acc[im][in] = __builtin_amdgcn_mfma_f32_16x16x32_bf16(
                    af[im], bf_[in], acc[im][in], 0, 0, 0);
    }

    const float scale = 0.08838834764831845f;
    float mloc[4][4];
#pragma unroll
    for (int im = 0; im < 4; ++im)
#pragma unroll
        for (int r = 0; r < 4; ++r) {
            float m = acc[im][0][r];
#pragma unroll
            for (int in = 1; in < 4; ++in) m = fmaxf(m, acc[im][in][r]);
            mloc[im][r] = m;
        }
#pragma unroll
    for (int mask = 1; mask < 16; mask <<= 1)
#pragma unroll
        for (int im = 0; im < 4; ++im)
#pragma unroll
            for (int r = 0; r < 4; ++r)
                mloc[im][r] = fmaxf(mloc[im][r], __shfl_xor(mloc[im][r], mask, 64));
    if (l15 == 0) {
#pragma unroll
        for (int im = 0; im < 4; ++im)
#pragma unroll
            for (int r = 0; r < 4; ++r)
                redm[nh * 128 + mh * 64 + im * 16 + quad * 4 + r] = mloc[im][r];
    }
    __syncthreads();
    float sloc[4][4];
#pragma unroll
    for (int im = 0; im < 4; ++im)
#pragma unroll
        for (int r = 0; r < 4; ++r) {
            int row = mh * 64 + im * 16 + quad * 4 + r;
            float m = fmaxf(redm[row], redm[128 + row]);
            float ss = 0.f;
#pragma unroll
            for (int in = 0; in < 4; ++in) {
                float e = __expf((acc[im][in][r] - m) * scale);
                acc[im][in][r] = e;
                ss += e;
            }
            sloc[im][r] = ss;
        }
#pragma unroll
    for (int mask = 1; mask < 16; mask <<= 1)
#pragma unroll
        for (int im = 0; im < 4; ++im)
#pragma unroll
            for (int r = 0; r < 4; ++r)
                sloc[im][r] += __shfl_xor(sloc[im][r], mask, 64);
    if (l15 == 0) {
#pragma unroll
        for (int im = 0; im < 4; ++im)
#pragma unroll
            for (int r = 0; r < 4; ++r)
                reds[nh * 128 + mh * 64 + im * 16 + quad * 4 + r] = sloc[im][r];
    }
    __syncthreads();
#pragma unroll
    for (int im = 0; im < 4; ++im)
#pragma unroll
        for (int r = 0; r < 4; ++r) {
            int row = mh * 64 + im * 16 + quad * 4 + r;
            float inv = 1.0f / (reds[row] + reds[128 + row]);
#pragma unroll
            for (int in = 0; in < 4; ++in) {
                int col = nh * 64 + in * 16 + l15;
                Pb[row * 136 + col] = f2bf(acc[im][in][r] * inv);
            }
        }
    __syncthreads();

    // ---- Phase 2: Y = P·vw (A=Pb, B=vT swizzled) + bo ----
    float bb[4];
#pragma unroll
    for (int in = 0; in < 4; ++in) bb[in] = bo[nh * 64 + in * 16 + l15];
#pragma unroll
    for (int im = 0; im < 4; ++im)
#pragma unroll
        for (int in = 0; in < 4; ++in)
            acc[im][in] = (floatx4){0.f, 0.f, 0.f, 0.f};
#pragma unroll
    for (int kc = 0; kc < 128; kc += 32) {
        short8 af[4], bf_[4];
#pragma unroll
        for (int im = 0; im < 4; ++im)
            af[im] = *reinterpret_cast<const short8*>(
                &Pb[(mh * 64 + im * 16 + l15) * 136 + kc + quad * 8]);
#pragma unroll
        for (int in = 0; in < 4; ++in) {
            int dRow = nh * 64 + in * 16 + l15;
            int cphys = (((kc >> 3) + quad) ^ (dRow >> 3)) & 15;
            bf_[in] = *reinterpret_cast<const short8*>(
                &vT[dRow * 136 + cphys * 8]);
        }
#pragma unroll
        for (int im = 0; im < 4; ++im)
#pragma unroll
            for (int in = 0; in < 4; ++in)
                acc[im][in] = __builtin_amdgcn_mfma_f32_16x16x32_bf16(
                    af[im], bf_[in], acc[im][in], 0, 0, 0);
    }
    __syncthreads();                             // Pb/vT reads done; Ystg aliases
#pragma unroll
    for (int im = 0; im < 4; ++im)
#pragma unroll
        for (int in = 0; in < 4; ++in) {
            int col = nh * 64 + in * 16 + l15;
#pragma unroll
            for (int r = 0; r < 4; ++r) {
                int row = mh * 64 + im * 16 + quad * 4 + r;
                Ystg[row * 132 + col] = acc[im][in][r] + bb[in];
            }
        }
    __syncthreads();
    // coalesced Y write: 4096 float4, 16/thread
    for (int id = t; id < 4096; id += 256) {
        int row = id >> 5, c4 = (id & 31) * 4;
        *reinterpret_cast<float4*>(outp + hb + (size_t)row * 128 + c4) =
            *reinterpret_cast<const float4*>(&Ystg[row * 132 + c4]);
    }
}

// ---------------------------------------------------------------------------
extern "C" void kernel_launch(void* const* d_in, const int* in_sizes, int n_in,
                              void* d_out, int out_size, void* d_ws, size_t ws_size,
                              hipStream_t stream) {
    const float* x   = (const float*)d_in[0];
    const float* Wq  = (const float*)d_in[2];
    const float* bq  = (const float*)d_in[3];
    const float* Wk  = (const float*)d_in[4];
    const float* bk  = (const float*)d_in[5];
    const float* Wv  = (const float*)d_in[6];
    const float* bv  = (const float*)d_in[7];
    const float* Wo  = (const float*)d_in[8];
    const float* bo  = (const float*)d_in[9];
    const float* Wc1 = (const float*)d_in[10];
    const float* bc1 = (const float*)d_in[11];
    const float* Wc2 = (const float*)d_in[12];
    const float* rel = (const float*)d_in[13];

    char* wsb = (char*)d_ws;
    short* q_bf  = (short*)(wsb);                       // 16 MB
    short* k_bf  = (short*)(wsb + 1ull * 16777216);
    short* v_bf  = (short*)(wsb + 2ull * 16777216);
    short* x_bf  = (short*)(wsb + 3ull * 16777216);
    float* P     = (float*)(wsb + 4ull * 16777216);     // 13.1 MB
    float* W2    = (float*)(wsb + 4ull * 16777216 + 13107200);
    float* cst   = W2 + 6400;
    float* b_eff = cst + 64;
    short* wbf   = (short*)(b_eff + 16);                // 4 x 16384 bf16
    short* w2h   = wbf + 65536;                         // 64x128 bf16 (hi)
    short* w2l   = w2h + 8192;                          // 64x128 bf16 (lo)
    float* outp  = (float*)d_out;

    hipLaunchKernelGGL(k_wprep,  dim3(82),   dim3(256), 0, stream, Wc1, Wc2, bc1, Wq, bq,
                       Wk, Wv, Wo, W2, cst, b_eff, wbf, w2h, w2l);
    hipLaunchKernelGGL(k_off,    dim3(512),  dim3(256), 0, stream, x, w2h, w2l, cst,
                       bq, wbf, P, x_bf, q_bf);
    hipLaunchKernelGGL(k_fused3, dim3(512),  dim3(256), 0, stream, P, b_eff, x_bf, wbf,
                       bk, bv, rel, k_bf, v_bf);
    hipLaunchKernelGGL(k_attn3,  dim3(512),  dim3(256), 0, stream, q_bf, k_bf, v_bf,
                       bo, outp);
}

// Round 11
// 199.645 us; speedup vs baseline: 1.0135x; 1.0135x over previous
//
#include <hip/hip_runtime.h>
#include <math.h>

// DeformAtten2D: B=4, H=W=C=128.
// R18: R17 post-mortem — per-wave dataflow was right (fused3 <41us) but
// holding k+v accumulators simultaneously cost ~200 VGPRs of live state.
// Fix: sequential per-wave GEMMs through ONE reused acc[2][8] (64 VGPR):
// gather(own rows, no barrier) -> k GEMM -> stage k->stg (barrier-free,
// per-wave cols, rowsP dead) -> v GEMM -> B3 -> stage v->xsT + k write ->
// B4 -> vw GEMM -> stage vw->stg (barrier-free) -> B5 -> vw write.
// Barriers 7->5; B-frags/iter 16->8; bit-identical accumulation order.
// k_off (R16, q fused), k_attn3 (R15), k_wprep unchanged.
#define IMG 16384   // 128*128

typedef short short4v __attribute__((ext_vector_type(4)));
typedef short short8  __attribute__((ext_vector_type(8)));
typedef float floatx4 __attribute__((ext_vector_type(4)));

__device__ __forceinline__ float4 ld4(const float* p) {
    return *reinterpret_cast<const float4*>(p);
}
__device__ __forceinline__ short f2bf(float f) {
    union { float f; unsigned u; } v; v.f = f;
    unsigned r = v.u + 0x7fffu + ((v.u >> 16) & 1u);   // RNE
    return (short)(r >> 16);
}
__device__ __forceinline__ float bf2f(short s) {
    union { unsigned u; float f; } v;
    v.u = ((unsigned)(unsigned short)s) << 16;
    return v.f;
}

// ---------------------------------------------------------------------------
// Kernel 1: blocks 0..49: o50=(t,tap) weight folding (W2, cst, b_eff) +
//           split-bf16 W2 (w2h/w2l). blocks 50..81: [Wq|Wk|Wv|Wo] -> bf16.
// ---------------------------------------------------------------------------
__launch_bounds__(256)
__global__ void k_wprep(const float* __restrict__ Wc1, const float* __restrict__ Wc2,
                        const float* __restrict__ bc1, const float* __restrict__ Wq,
                        const float* __restrict__ bq, const float* __restrict__ Wk,
                        const float* __restrict__ Wv, const float* __restrict__ Wo,
                        float* __restrict__ W2, float* __restrict__ cst,
                        float* __restrict__ b_eff, short* __restrict__ wbf,
                        short* __restrict__ w2h, short* __restrict__ w2l) {
    const int t = threadIdx.x;
    if (blockIdx.x >= 50) {                  // weight bf16 conversion
        if (blockIdx.x == 50) {              // zero-pad W2 split rows 50..63
            for (int i = t; i < 14 * 128; i += 256) {
                w2h[6400 + i] = 0;
                w2l[6400 + i] = 0;
            }
        }
        int i = (blockIdx.x - 50) * 256 + t;  // < 8192
        int base = i * 8;
        int sel = base >> 14, off = base & 16383;
        const float* s = (sel == 0) ? Wq : (sel == 1) ? Wk : (sel == 2) ? Wv : Wo;
        float4 a = ld4(s + off), b = ld4(s + off + 4);
        short8 o;
        o[0] = f2bf(a.x); o[1] = f2bf(a.y); o[2] = f2bf(a.z); o[3] = f2bf(a.w);
        o[4] = f2bf(b.x); o[5] = f2bf(b.y); o[6] = f2bf(b.z); o[7] = f2bf(b.w);
        *reinterpret_cast<short8*>(wbf + base) = o;
        return;
    }
    __shared__ float U[128];
    __shared__ float red[256];
    __shared__ float wc2[128];
    __shared__ float bql[128];
    const int tt = blockIdx.x;               // 0..49
    const int tch = tt / 25, tap = tt % 25;
    if (t < 128) { wc2[t] = Wc2[tch * 128 + t]; bql[t] = bq[t]; }
    __syncthreads();
    const int c = t & 127, half = t >> 7;
    float p = 0.f;
    for (int o = half * 64; o < half * 64 + 64; ++o)
        p += wc2[o] * Wc1[(o * 128 + c) * 25 + tap];
    red[half * 128 + c] = p;
    __syncthreads();
    if (t < 128) U[t] = red[t] + red[128 + t];
    __syncthreads();
    float p2 = 0.f;
    for (int cc = half * 64; cc < half * 64 + 64; ++cc)
        p2 += U[cc] * Wq[cc * 128 + c];
    red[half * 128 + c] = p2;
    __syncthreads();
    if (t < 128) {
        float vv = red[t] + red[128 + t];
        W2[tt * 128 + t] = vv;
        short hh = f2bf(vv);
        w2h[tt * 128 + t] = hh;
        w2l[tt * 128 + t] = f2bf(vv - bf2f(hh));
    }
    if (t < 128) red[t] = U[t] * bql[t];
    __syncthreads();
    if (t == 0) {
        float s = 0.f;
        for (int j = 0; j < 128; ++j) s += red[j];
        cst[tt] = s;
    }
    if (tap == 0) {
        __syncthreads();
        if (t < 128) red[t] = wc2[t] * bc1[t];
        __syncthreads();
        if (t == 0) {
            float s = 0.f;
            for (int j = 0; j < 128; ++j) s += red[j];
            b_eff[tch] = s;
        }
    }
}

// ---------------------------------------------------------------------------
// Kernel 2 (R16): P[b][o50][pix] = W2·x + cst (split-bf16 hh+hl+lh) AND
// q[b][o][pix] = x·Wq^T + bq (bf16). 512 blocks; block = one (b,h) row.
// ---------------------------------------------------------------------------
__launch_bounds__(256, 2)
__global__ void k_off(const float* __restrict__ x, const short* __restrict__ w2h,
                      const short* __restrict__ w2l, const float* __restrict__ cst,
                      const float* __restrict__ bq, const short* __restrict__ wbf,
                      float* __restrict__ P, short* __restrict__ x_bf,
                      short* __restrict__ q_bf) {
    __shared__ __align__(16) char smem[34816];
    float* stageF = (float*)smem;                 // 64x132 fp32 (P) = 33792 B
    short* stageS = (short*)smem;                 // 128x136 bf16 (q) = 34816 B
    const int t = threadIdx.x;
    const int w = t >> 6, l = t & 63, l15 = l & 15, quad = l >> 4;
    const int p0 = blockIdx.x * 128;
    const int b = p0 >> 14, pix0 = p0 & (IMG - 1);
    const int h = pix0 >> 7;                      // image row of this block

    floatx4 accP[2][4];
    floatx4 accQ[2][8];
#pragma unroll
    for (int im = 0; im < 2; ++im) {
#pragma unroll
        for (int in = 0; in < 4; ++in) accP[im][in] = (floatx4){0.f, 0.f, 0.f, 0.f};
#pragma unroll
        for (int in = 0; in < 8; ++in) accQ[im][in] = (floatx4){0.f, 0.f, 0.f, 0.f};
    }

    const float* xb = x + (size_t)p0 * 128;
    short* xbb = x_bf + (size_t)p0 * 128;

#pragma unroll
    for (int kc = 0; kc < 128; kc += 32) {
        short8 ah[2], al[2];
#pragma unroll
        for (int im = 0; im < 2; ++im) {
            int row = w * 32 + im * 16 + l15;
            const float* src = xb + row * 128 + kc + quad * 8;
            float4 f0 = ld4(src), f1 = ld4(src + 4);
            float fv[8] = {f0.x, f0.y, f0.z, f0.w, f1.x, f1.y, f1.z, f1.w};
            short8 h8, l8;
#pragma unroll
            for (int r = 0; r < 8; ++r) {
                short hh = f2bf(fv[r]);
                h8[r] = hh;
                l8[r] = f2bf(fv[r] - bf2f(hh));
            }
            ah[im] = h8; al[im] = l8;
            *reinterpret_cast<short8*>(xbb + row * 128 + kc + quad * 8) = h8;
        }
        short8 bh[4], bl[4], bqf[8];
#pragma unroll
        for (int in = 0; in < 4; ++in) {
            int o = in * 16 + l15;
            bh[in] = *reinterpret_cast<const short8*>(w2h + o * 128 + kc + quad * 8);
            bl[in] = *reinterpret_cast<const short8*>(w2l + o * 128 + kc + quad * 8);
        }
#pragma unroll
        for (int in = 0; in < 8; ++in)
            bqf[in] = *reinterpret_cast<const short8*>(
                wbf + (in * 16 + l15) * 128 + kc + quad * 8);
#pragma unroll
        for (int im = 0; im < 2; ++im) {
#pragma unroll
            for (int in = 0; in < 4; ++in) {
                accP[im][in] = __builtin_amdgcn_mfma_f32_16x16x32_bf16(
                    ah[im], bh[in], accP[im][in], 0, 0, 0);
                accP[im][in] = __builtin_amdgcn_mfma_f32_16x16x32_bf16(
                    ah[im], bl[in], accP[im][in], 0, 0, 0);
                accP[im][in] = __builtin_amdgcn_mfma_f32_16x16x32_bf16(
                    al[im], bh[in], accP[im][in], 0, 0, 0);
            }
#pragma unroll
            for (int in = 0; in < 8; ++in)
                accQ[im][in] = __builtin_amdgcn_mfma_f32_16x16x32_bf16(
                    ah[im], bqf[in], accQ[im][in], 0, 0, 0);
        }
    }
    // ---- stage P tile (o 0..63 x px 0..127) then coalesced write of o<50 ----
#pragma unroll
    for (int im = 0; im < 2; ++im)
#pragma unroll
        for (int in = 0; in < 4; ++in) {
            int o = in * 16 + l15;
            int row0 = w * 32 + im * 16 + quad * 4;
            *reinterpret_cast<float4*>(&stageF[o * 132 + row0]) =
                make_float4(accP[im][in][0], accP[im][in][1],
                            accP[im][in][2], accP[im][in][3]);
        }
    __syncthreads();
    for (int id = t; id < 50 * 32; id += 256) {
        int o = id >> 5, px4 = (id & 31) * 4;
        float c = cst[o];
        float4 v = *reinterpret_cast<float4*>(&stageF[o * 132 + px4]);
        v.x += c; v.y += c; v.z += c; v.w += c;
        *reinterpret_cast<float4*>(P + ((size_t)(b * 50 + o)) * IMG + pix0 + px4) = v;
    }
    __syncthreads();                              // stageF reads done
    // ---- stage q bf16 (o 0..127 x px 0..127) ----
#pragma unroll
    for (int in = 0; in < 8; ++in) {
        int o = in * 16 + l15;
        float bb = bq[o];
#pragma unroll
        for (int im = 0; im < 2; ++im) {
            int row0 = w * 32 + im * 16 + quad * 4;
            short4v s = {f2bf(accQ[im][in][0] + bb), f2bf(accQ[im][in][1] + bb),
                         f2bf(accQ[im][in][2] + bb), f2bf(accQ[im][in][3] + bb)};
            *reinterpret_cast<short4v*>(&stageS[o * 136 + row0]) = s;
        }
    }
    __syncthreads();
    // coalesced q write
    for (int id = t; id < 2048; id += 256) {
        int o = id >> 4, seg = id & 15;
        *reinterpret_cast<short8*>(
            q_bf + ((size_t)(b * 128 + o)) * IMG + h * 128 + seg * 8)
            = *reinterpret_cast<const short8*>(&stageS[o * 136 + seg * 8]);
    }
}

// ---------------------------------------------------------------------------
// Kernel 3 (R18): FUSED per (b,h) row, 256 threads, 5 barriers, per-wave
// dataflow with ONE reused acc[2][8]:
//   A: P halo -> conv -> offsets; B1/B2.
//   B: per-wave gather (rows w*32..+31) -> xsT (no barrier).
//   C: per-wave k GEMM -> stage k->stg (barrier-free) -> per-wave v GEMM
//      (reuse acc) -> B3 -> stage v->xsT + k write -> B4 -> per-wave vw GEMM
//      (reuse acc) -> stage vw->stg (barrier-free) -> B5 -> vw write.
// LDS: stg/rowsP 34816 + xsT 34816 + offs 1024 = 70656 B (2 blocks/CU).
// ---------------------------------------------------------------------------
__launch_bounds__(256, 2)
__global__ void k_fused3(const float* __restrict__ P, const float* __restrict__ b_eff,
                         const short* __restrict__ x_bf, const short* __restrict__ wbf,
                         const float* __restrict__ bk, const float* __restrict__ bv,
                         const float* __restrict__ rel,
                         short* __restrict__ k_bf, short* __restrict__ v_bf) {
    __shared__ __align__(16) char smem[70656];
    float* rowsP  = (float*)smem;                // 27200 B (phase A only)
    short* stg    = (short*)smem;                // 34816 B stage (aliases rowsP)
    short* xsT    = (short*)(smem + 34816);      // 34816 B
    float* offs_l = (float*)(smem + 69632);      // 1024 B

    const int t = threadIdx.x;
    const int w = t >> 6, l = t & 63, l15 = l & 15, quad = l >> 4;
    const int bh = blockIdx.x;
    const int b = bh >> 7, h = bh & 127;

    // ---- Phase A: P rows (5-row halo), branch-free clamped loads ----
    for (int id = t; id < 1600; id += 256) {
        int o = id >> 5, q4 = (id & 31) * 4;
        int di = (o % 25) / 5;
        int r = h + di - 2;
        int rc = min(max(r, 0), 127);
        float4 v = ld4(P + ((size_t)(b * 50 + o)) * IMG + rc * 128 + q4);
        float m = (r >= 0 && r < 128) ? 1.f : 0.f;
        v.x *= m; v.y *= m; v.z *= m; v.w *= m;
        *reinterpret_cast<float4*>(&rowsP[o * 136 + 4 + q4]) = v;
    }
    // zero the 4-col halos (cols 0..3 and 132..135) of each of 50 planes
    for (int id = t; id < 400; id += 256) {
        int o = id >> 3, c = id & 7;
        rowsP[o * 136 + (c < 4 ? c : 128 + c)] = 0.f;
    }
    __syncthreads();                             // B1
    {
        int wp = t & 127, tc = t >> 7;
        float acc = 0.f;
#pragma unroll
        for (int di = 0; di < 5; ++di)
#pragma unroll
            for (int dj = 0; dj < 5; ++dj)
                acc += rowsP[(tc * 25 + di * 5 + dj) * 136 + wp + dj + 2];
        offs_l[tc * 128 + wp] = tanhf(acc + b_eff[tc]) * 5.0f;
    }
    __syncthreads();                             // B2: offs ready, rowsP dead

    // ---- Phase B: per-wave branch-free gather -> xsT (NO barrier) ----
    {
        const short* xbase = x_bf + (size_t)b * IMG * 128;
#pragma unroll
        for (int it = 0; it < 8; ++it) {
            int local = l + it * 64;             // 0..511 within wave
            int px = w * 32 + (local >> 4);      // wave's own rows
            int c8 = local & 15;
            float ox = offs_l[px];
            float oy = offs_l[128 + px];
            float xg = ((float)px + ox) * (128.0f / 127.0f) - 0.5f;
            float yg = ((float)h  + oy) * (128.0f / 127.0f) - 0.5f;
            float x0f = floorf(xg), y0f = floorf(yg);
            float fx = xg - x0f, fy = yg - y0f;
            int x0 = (int)x0f, y0 = (int)y0f;
            float s[8];
#pragma unroll
            for (int r = 0; r < 8; ++r) s[r] = 0.f;
#pragma unroll
            for (int tap = 0; tap < 4; ++tap) {
                int xi = x0 + (tap & 1), yi = y0 + (tap >> 1);
                float wgt = ((tap & 1) ? fx : 1.f - fx) * ((tap >> 1) ? fy : 1.f - fy);
                wgt = (xi >= 0 && xi < 128 && yi >= 0 && yi < 128) ? wgt : 0.f;
                int xc = min(max(xi, 0), 127), yc = min(max(yi, 0), 127);
                short8 v = *reinterpret_cast<const short8*>(
                    xbase + ((size_t)(yc * 128 + xc)) * 128 + c8 * 8);
#pragma unroll
                for (int r = 0; r < 8; ++r) s[r] = fmaf(wgt, bf2f(v[r]), s[r]);
            }
            short8 o;
#pragma unroll
            for (int r = 0; r < 8; ++r) o[r] = f2bf(s[r]);
            *reinterpret_cast<short8*>(&xsT[px * 136 + c8 * 8]) = o;
        }
    }

    floatx4 acc[2][8];

    // ---- per-wave k GEMM (A-rows = wave's gathered rows) ----
#pragma unroll
    for (int im = 0; im < 2; ++im)
#pragma unroll
        for (int in = 0; in < 8; ++in) acc[im][in] = (floatx4){0.f, 0.f, 0.f, 0.f};
#pragma unroll
    for (int kc = 0; kc < 128; kc += 32) {
        short8 af[2], bfr[8];
#pragma unroll
        for (int im = 0; im < 2; ++im)
            af[im] = *reinterpret_cast<const short8*>(
                &xsT[(w * 32 + im * 16 + l15) * 136 + kc + quad * 8]);
#pragma unroll
        for (int in = 0; in < 8; ++in)
            bfr[in] = *reinterpret_cast<const short8*>(
                wbf + 16384 + (in * 16 + l15) * 128 + kc + quad * 8);
#pragma unroll
        for (int im = 0; im < 2; ++im)
#pragma unroll
            for (int in = 0; in < 8; ++in)
                acc[im][in] = __builtin_amdgcn_mfma_f32_16x16x32_bf16(
                    af[im], bfr[in], acc[im][in], 0, 0, 0);
    }
    // stage k -> stg (per-wave columns; rowsP dead; no readers yet -> no barrier)
#pragma unroll
    for (int in = 0; in < 8; ++in) {
        int o = in * 16 + l15;
        float bbk = bk[o];
#pragma unroll
        for (int im = 0; im < 2; ++im) {
            int row0 = w * 32 + im * 16 + quad * 4;
            short4v sk = {f2bf(acc[im][in][0] + bbk), f2bf(acc[im][in][1] + bbk),
                          f2bf(acc[im][in][2] + bbk), f2bf(acc[im][in][3] + bbk)};
            *reinterpret_cast<short4v*>(&stg[o * 136 + row0]) = sk;
        }
    }

    // ---- per-wave v GEMM (reuse acc) ----
#pragma unroll
    for (int im = 0; im < 2; ++im)
#pragma unroll
        for (int in = 0; in < 8; ++in) acc[im][in] = (floatx4){0.f, 0.f, 0.f, 0.f};
#pragma unroll
    for (int kc = 0; kc < 128; kc += 32) {
        short8 af[2], bfr[8];
#pragma unroll
        for (int im = 0; im < 2; ++im)
            af[im] = *reinterpret_cast<const short8*>(
                &xsT[(w * 32 + im * 16 + l15) * 136 + kc + quad * 8]);
#pragma unroll
        for (int in = 0; in < 8; ++in)
            bfr[in] = *reinterpret_cast<const short8*>(
                wbf + 32768 + (in * 16 + l15) * 128 + kc + quad * 8);
#pragma unroll
        for (int im = 0; im < 2; ++im)
#pragma unroll
            for (int in = 0; in < 8; ++in)
                acc[im][in] = __builtin_amdgcn_mfma_f32_16x16x32_bf16(
                    af[im], bfr[in], acc[im][in], 0, 0, 0);
    }
    __syncthreads();                             // B3: all gather reads + k staged
    // stage biased v -> xsT (overwrites gathered data, safe after B3)
#pragma unroll
    for (int in = 0; in < 8; ++in) {
        int o = in * 16 + l15;
        float bbv = bv[o] + rel[o * 128 + h];
#pragma unroll
        for (int im = 0; im < 2; ++im) {
            int row0 = w * 32 + im * 16 + quad * 4;
            short4v sv = {f2bf(acc[im][in][0] + bbv), f2bf(acc[im][in][1] + bbv),
                          f2bf(acc[im][in][2] + bbv), f2bf(acc[im][in][3] + bbv)};
            *reinterpret_cast<short4v*>(&xsT[o * 136 + row0]) = sv;
        }
    }
    // coalesced k write (stg complete as of B3)
    for (int id = t; id < 2048; id += 256) {
        int o = id >> 4, seg = id & 15;
        *reinterpret_cast<short8*>(
            k_bf + ((size_t)(b * 128 + o)) * IMG + h * 128 + seg * 8)
            = *reinterpret_cast<const short8*>(&stg[o * 136 + seg * 8]);
    }
    __syncthreads();                             // B4: v staged; k-write stg reads done

    // ---- per-wave vw = v·Wo^T GEMM (reuse acc): D[o' rows w*32..+31][plane] ----
    {
        const short* WoB = wbf + 49152;
#pragma unroll
        for (int im = 0; im < 2; ++im)
#pragma unroll
            for (int in = 0; in < 8; ++in) acc[im][in] = (floatx4){0.f, 0.f, 0.f, 0.f};
#pragma unroll
        for (int kc = 0; kc < 128; kc += 32) {
            short8 af[2], bfr[8];
#pragma unroll
            for (int im = 0; im < 2; ++im)
                af[im] = *reinterpret_cast<const short8*>(
                    WoB + (w * 32 + im * 16 + l15) * 128 + kc + quad * 8);
#pragma unroll
            for (int in = 0; in < 8; ++in)
                bfr[in] = *reinterpret_cast<const short8*>(
                    &xsT[(in * 16 + l15) * 136 + kc + quad * 8]);
#pragma unroll
            for (int im = 0; im < 2; ++im)
#pragma unroll
                for (int in = 0; in < 8; ++in)
                    acc[im][in] = __builtin_amdgcn_mfma_f32_16x16x32_bf16(
                        af[im], bfr[in], acc[im][in], 0, 0, 0);
        }
        // stage vw -> stg (per-wave cols; stg's last reads finished before B4)
#pragma unroll
        for (int in = 0; in < 8; ++in) {
            int plane = in * 16 + l15;
#pragma unroll
            for (int im = 0; im < 2; ++im) {
                int row0 = w * 32 + im * 16 + quad * 4;    // o' base
                short4v s = {f2bf(acc[im][in][0]), f2bf(acc[im][in][1]),
                             f2bf(acc[im][in][2]), f2bf(acc[im][in][3])};
                *reinterpret_cast<short4v*>(&stg[plane * 136 + row0]) = s;
            }
        }
    }
    __syncthreads();                             // B5
    // coalesced vw write into v_bf
    for (int id = t; id < 2048; id += 256) {
        int o = id >> 4, seg = id & 15;
        *reinterpret_cast<short8*>(
            v_bf + ((size_t)(b * 128 + o)) * IMG + h * 128 + seg * 8)
            = *reinterpret_cast<const short8*>(&stg[o * 136 + seg * 8]);
    }
}

// ---------------------------------------------------------------------------
// Kernel 4 (R15): MFMA attention, 2 phases. Phase 1: S=q·kT + softmax.
// Phase 2: Y = P·vw + bo (Wo pre-folded into vw by k_fused3). b64-packed
// vw->vT transpose; Y staged fp32 in LDS -> coalesced float4 stores.
// LDS: Pb 34816 + vT 34816 + redm 1024 + reds 1024 = 71680 B (2 blocks/CU).
// ---------------------------------------------------------------------------
__launch_bounds__(256, 2)
__global__ void k_attn3(const short* __restrict__ q_bf, const short* __restrict__ k_bf,
                        const short* __restrict__ v_bf,
                        const float* __restrict__ bo, float* __restrict__ outp) {
    __shared__ __align__(16) char smem[71680];
    short* Pb   = (short*)smem;                  // 34816 B: P bf16
    short* vT   = (short*)(smem + 34816);        // 34816 B: vw^T swizzled
    float* Ystg = (float*)smem;                  // 128x132 fp32 = 67584 B (epilogue)
    float* redm = (float*)(smem + 69632);        // 512 B x2
    float* reds = (float*)(smem + 70656);        // 512 B x2

    const int t = threadIdx.x;
    const int w = t >> 6, l = t & 63, l15 = l & 15, quad = l >> 4;
    const int mh = w >> 1, nh = w & 1;
    const size_t hb = (size_t)blockIdx.x * IMG;
    const short* qp = q_bf + hb;
    const short* kp = k_bf + hb;
    const short* vp = v_bf + hb;

    // ---- vw -> vT transpose (b64 writes, swizzled): 512 items, 2/thread ----
    for (int id = t; id < 512; id += 256) {
        int j4 = id >> 4, seg = id & 15;             // j-block of 4, d-block of 8
        const short* src = vp + (j4 * 4) * 128 + seg * 8;
        short8 v0 = *reinterpret_cast<const short8*>(src);
        short8 v1 = *reinterpret_cast<const short8*>(src + 128);
        short8 v2 = *reinterpret_cast<const short8*>(src + 256);
        short8 v3 = *reinterpret_cast<const short8*>(src + 384);
        int phys = (((j4 >> 1) ^ seg) & 15) * 8 + (j4 & 1) * 4;
#pragma unroll
        for (int r = 0; r < 8; ++r) {
            short4v wv = {v0[r], v1[r], v2[r], v3[r]};
            *reinterpret_cast<short4v*>(&vT[(seg * 8 + r) * 136 + phys]) = wv;
        }
    }

    floatx4 acc[4][4];
#pragma unroll
    for (int im = 0; im < 4; ++im)
#pragma unroll
        for (int in = 0; in < 4; ++in)
            acc[im][in] = (floatx4){0.f, 0.f, 0.f, 0.f};

    // ---- Phase 1: S = q·kT (direct-global frags) ----
#pragma unroll
    for (int kc = 0; kc < 128; kc += 32) {
        short8 af[4], bf_[4];
#pragma unroll
        for (int im = 0; im < 4; ++im)
            af[im] = *reinterpret_cast<const short8*>(
                qp + (mh * 64 + im * 16 + l15) * 128 + kc + quad * 8);
#pragma unroll
        for (int in = 0; in < 4; ++in)
            bf_[in] = *reinterpret_cast<const short8*>(
                kp + (nh * 64 + in * 16 + l15) * 128 + kc + quad * 8);
#pragma unroll
        for (int im = 0; im < 4; ++im)
#pragma unroll
            for (int in = 0; in < 4; ++in)
                acc[im][in] = __builtin_amdgcn_mfma_f32_16x16x32_bf16(
                    af[im], bf_[in], acc[im][in], 0, 0, 0);
    }

    const float scale = 0.08838834764831845f;
    float mloc[4][4];
#pragma unroll
    for (int im = 0; im < 4; ++im)
#pragma unroll
        for (int r = 0; r < 4; ++r) {
            float m = acc[im][0][r];
#pragma unroll
            for (int in = 1; in < 4; ++in) m = fmaxf(m, acc[im][in][r]);
            mloc[im][r] = m;
        }
#pragma unroll
    for (int mask = 1; mask < 16; mask <<= 1)
#pragma unroll
        for (int im = 0; im < 4; ++im)
#pragma unroll
            for (int r = 0; r < 4; ++r)
                mloc[im][r] = fmaxf(mloc[im][r], __shfl_xor(mloc[im][r], mask, 64));
    if (l15 == 0) {
#pragma unroll
        for (int im = 0; im < 4; ++im)
#pragma unroll
            for (int r = 0; r < 4; ++r)
                redm[nh * 128 + mh * 64 + im * 16 + quad * 4 + r] = mloc[im][r];
    }
    __syncthreads();
    float sloc[4][4];
#pragma unroll
    for (int im = 0; im < 4; ++im)
#pragma unroll
        for (int r = 0; r < 4; ++r) {
            int row = mh * 64 + im * 16 + quad * 4 + r;
            float m = fmaxf(redm[row], redm[128 + row]);
            float ss = 0.f;
#pragma unroll
            for (int in = 0; in < 4; ++in) {
                float e = __expf((acc[im][in][r] - m) * scale);
                acc[im][in][r] = e;
                ss += e;
            }
            sloc[im][r] = ss;
        }
#pragma unroll
    for (int mask = 1; mask < 16; mask <<= 1)
#pragma unroll
        for (int im = 0; im < 4; ++im)
#pragma unroll
            for (int r = 0; r < 4; ++r)
                sloc[im][r] += __shfl_xor(sloc[im][r], mask, 64);
    if (l15 == 0) {
#pragma unroll
        for (int im = 0; im < 4; ++im)
#pragma unroll
            for (int r = 0; r < 4; ++r)
                reds[nh * 128 + mh * 64 + im * 16 + quad * 4 + r] = sloc[im][r];
    }
    __syncthreads();
#pragma unroll
    for (int im = 0; im < 4; ++im)
#pragma unroll
        for (int r = 0; r < 4; ++r) {
            int row = mh * 64 + im * 16 + quad * 4 + r;
            float inv = 1.0f / (reds[row] + reds[128 + row]);
#pragma unroll
            for (int in = 0; in < 4; ++in) {
                int col = nh * 64 + in * 16 + l15;
                Pb[row * 136 + col] = f2bf(acc[im][in][r] * inv);
            }
        }
    __syncthreads();

    // ---- Phase 2: Y = P·vw (A=Pb, B=vT swizzled) + bo ----
    float bb[4];
#pragma unroll
    for (int in = 0; in < 4; ++in) bb[in] = bo[nh * 64 + in * 16 + l15];
#pragma unroll
    for (int im = 0; im < 4; ++im)
#pragma unroll
        for (int in = 0; in < 4; ++in)
            acc[im][in] = (floatx4){0.f, 0.f, 0.f, 0.f};
#pragma unroll
    for (int kc = 0; kc < 128; kc += 32) {
        short8 af[4], bf_[4];
#pragma unroll
        for (int im = 0; im < 4; ++im)
            af[im] = *reinterpret_cast<const short8*>(
                &Pb[(mh * 64 + im * 16 + l15) * 136 + kc + quad * 8]);
#pragma unroll
        for (int in = 0; in < 4; ++in) {
            int dRow = nh * 64 + in * 16 + l15;
            int cphys = (((kc >> 3) + quad) ^ (dRow >> 3)) & 15;
            bf_[in] = *reinterpret_cast<const short8*>(
                &vT[dRow * 136 + cphys * 8]);
        }
#pragma unroll
        for (int im = 0; im < 4; ++im)
#pragma unroll
            for (int in = 0; in < 4; ++in)
                acc[im][in] = __builtin_amdgcn_mfma_f32_16x16x32_bf16(
                    af[im], bf_[in], acc[im][in], 0, 0, 0);
    }
    __syncthreads();                             // Pb/vT reads done; Ystg aliases
#pragma unroll
    for (int im = 0; im < 4; ++im)
#pragma unroll
        for (int in = 0; in < 4; ++in) {
            int col = nh * 64 + in * 16 + l15;
#pragma unroll
            for (int r = 0; r < 4; ++r) {
                int row = mh * 64 + im * 16 + quad * 4 + r;
                Ystg[row * 132 + col] = acc[im][in][r] + bb[in];
            }
        }
    __syncthreads();
    // coalesced Y write: 4096 float4, 16/thread
    for (int id = t; id < 4096; id += 256) {
        int row = id >> 5, c4 = (id & 31) * 4;
        *reinterpret_cast<float4*>(outp + hb + (size_t)row * 128 + c4) =
            *reinterpret_cast<const float4*>(&Ystg[row * 132 + c4]);
    }
}

// ---------------------------------------------------------------------------
extern "C" void kernel_launch(void* const* d_in, const int* in_sizes, int n_in,
                              void* d_out, int out_size, void* d_ws, size_t ws_size,
                              hipStream_t stream) {
    const float* x   = (const float*)d_in[0];
    const float* Wq  = (const float*)d_in[2];
    const float* bq  = (const float*)d_in[3];
    const float* Wk  = (const float*)d_in[4];
    const float* bk  = (const float*)d_in[5];
    const float* Wv  = (const float*)d_in[6];
    const float* bv  = (const float*)d_in[7];
    const float* Wo  = (const float*)d_in[8];
    const float* bo  = (const float*)d_in[9];
    const float* Wc1 = (const float*)d_in[10];
    const float* bc1 = (const float*)d_in[11];
    const float* Wc2 = (const float*)d_in[12];
    const float* rel = (const float*)d_in[13];

    char* wsb = (char*)d_ws;
    short* q_bf  = (short*)(wsb);                       // 16 MB
    short* k_bf  = (short*)(wsb + 1ull * 16777216);
    short* v_bf  = (short*)(wsb + 2ull * 16777216);
    short* x_bf  = (short*)(wsb + 3ull * 16777216);
    float* P     = (float*)(wsb + 4ull * 16777216);     // 13.1 MB
    float* W2    = (float*)(wsb + 4ull * 16777216 + 13107200);
    float* cst   = W2 + 6400;
    float* b_eff = cst + 64;
    short* wbf   = (short*)(b_eff + 16);                // 4 x 16384 bf16
    short* w2h   = wbf + 65536;                         // 64x128 bf16 (hi)
    short* w2l   = w2h + 8192;                          // 64x128 bf16 (lo)
    float* outp  = (float*)d_out;

    hipLaunchKernelGGL(k_wprep,  dim3(82),   dim3(256), 0, stream, Wc1, Wc2, bc1, Wq, bq,
                       Wk, Wv, Wo, W2, cst, b_eff, wbf, w2h, w2l);
    hipLaunchKernelGGL(k_off,    dim3(512),  dim3(256), 0, stream, x, w2h, w2l, cst,
                       bq, wbf, P, x_bf, q_bf);
    hipLaunchKernelGGL(k_fused3, dim3(512),  dim3(256), 0, stream, P, b_eff, x_bf, wbf,
                       bk, bv, rel, k_bf, v_bf);
    hipLaunchKernelGGL(k_attn3,  dim3(512),  dim3(256), 0, stream, q_bf, k_bf, v_bf,
                       bo, outp);
}

// Round 12
// 199.145 us; speedup vs baseline: 1.0160x; 1.0025x over previous
//
#include <hip/hip_runtime.h>
#include <math.h>

// DeformAtten2D: B=4, H=W=C=128.
// R19: plateau-attack round (all results since R11 sit in a 196-205 noise
// band; fills ~103us of total are harness-fixed). Two barrier removals via
// the only lever that ever won (per-wave chain shortening):
// (1) k_fused3: per-wave P-halo load (cols w*32-4..+36, halo float4s
//     duplicate-written with identical values - benign) + per-wave conv
//     (own cols, bit-identical tap order) -> B1 removed, front is
//     barrier-free wave-drift. Barriers 5->4.
// (2) k_attn3: merged softmax - each half computes (m_half, sum e^(x-m_half))
//     pre-barrier, ONE barrier, per-row rescale e^(m_half-mg)/s_g.
//     Barriers 5->4. ~1ulp rounding change.
// k_off (R16, q fused), k_wprep unchanged.
#define IMG 16384   // 128*128

typedef short short4v __attribute__((ext_vector_type(4)));
typedef short short8  __attribute__((ext_vector_type(8)));
typedef float floatx4 __attribute__((ext_vector_type(4)));

__device__ __forceinline__ float4 ld4(const float* p) {
    return *reinterpret_cast<const float4*>(p);
}
__device__ __forceinline__ short f2bf(float f) {
    union { float f; unsigned u; } v; v.f = f;
    unsigned r = v.u + 0x7fffu + ((v.u >> 16) & 1u);   // RNE
    return (short)(r >> 16);
}
__device__ __forceinline__ float bf2f(short s) {
    union { unsigned u; float f; } v;
    v.u = ((unsigned)(unsigned short)s) << 16;
    return v.f;
}

// ---------------------------------------------------------------------------
// Kernel 1: blocks 0..49: o50=(t,tap) weight folding (W2, cst, b_eff) +
//           split-bf16 W2 (w2h/w2l). blocks 50..81: [Wq|Wk|Wv|Wo] -> bf16.
// ---------------------------------------------------------------------------
__launch_bounds__(256)
__global__ void k_wprep(const float* __restrict__ Wc1, const float* __restrict__ Wc2,
                        const float* __restrict__ bc1, const float* __restrict__ Wq,
                        const float* __restrict__ bq, const float* __restrict__ Wk,
                        const float* __restrict__ Wv, const float* __restrict__ Wo,
                        float* __restrict__ W2, float* __restrict__ cst,
                        float* __restrict__ b_eff, short* __restrict__ wbf,
                        short* __restrict__ w2h, short* __restrict__ w2l) {
    const int t = threadIdx.x;
    if (blockIdx.x >= 50) {                  // weight bf16 conversion
        if (blockIdx.x == 50) {              // zero-pad W2 split rows 50..63
            for (int i = t; i < 14 * 128; i += 256) {
                w2h[6400 + i] = 0;
                w2l[6400 + i] = 0;
            }
        }
        int i = (blockIdx.x - 50) * 256 + t;  // < 8192
        int base = i * 8;
        int sel = base >> 14, off = base & 16383;
        const float* s = (sel == 0) ? Wq : (sel == 1) ? Wk : (sel == 2) ? Wv : Wo;
        float4 a = ld4(s + off), b = ld4(s + off + 4);
        short8 o;
        o[0] = f2bf(a.x); o[1] = f2bf(a.y); o[2] = f2bf(a.z); o[3] = f2bf(a.w);
        o[4] = f2bf(b.x); o[5] = f2bf(b.y); o[6] = f2bf(b.z); o[7] = f2bf(b.w);
        *reinterpret_cast<short8*>(wbf + base) = o;
        return;
    }
    __shared__ float U[128];
    __shared__ float red[256];
    __shared__ float wc2[128];
    __shared__ float bql[128];
    const int tt = blockIdx.x;               // 0..49
    const int tch = tt / 25, tap = tt % 25;
    if (t < 128) { wc2[t] = Wc2[tch * 128 + t]; bql[t] = bq[t]; }
    __syncthreads();
    const int c = t & 127, half = t >> 7;
    float p = 0.f;
    for (int o = half * 64; o < half * 64 + 64; ++o)
        p += wc2[o] * Wc1[(o * 128 + c) * 25 + tap];
    red[half * 128 + c] = p;
    __syncthreads();
    if (t < 128) U[t] = red[t] + red[128 + t];
    __syncthreads();
    float p2 = 0.f;
    for (int cc = half * 64; cc < half * 64 + 64; ++cc)
        p2 += U[cc] * Wq[cc * 128 + c];
    red[half * 128 + c] = p2;
    __syncthreads();
    if (t < 128) {
        float vv = red[t] + red[128 + t];
        W2[tt * 128 + t] = vv;
        short hh = f2bf(vv);
        w2h[tt * 128 + t] = hh;
        w2l[tt * 128 + t] = f2bf(vv - bf2f(hh));
    }
    if (t < 128) red[t] = U[t] * bql[t];
    __syncthreads();
    if (t == 0) {
        float s = 0.f;
        for (int j = 0; j < 128; ++j) s += red[j];
        cst[tt] = s;
    }
    if (tap == 0) {
        __syncthreads();
        if (t < 128) red[t] = wc2[t] * bc1[t];
        __syncthreads();
        if (t == 0) {
            float s = 0.f;
            for (int j = 0; j < 128; ++j) s += red[j];
            b_eff[tch] = s;
        }
    }
}

// ---------------------------------------------------------------------------
// Kernel 2 (R16): P[b][o50][pix] = W2·x + cst (split-bf16 hh+hl+lh) AND
// q[b][o][pix] = x·Wq^T + bq (bf16). 512 blocks; block = one (b,h) row.
// ---------------------------------------------------------------------------
__launch_bounds__(256, 2)
__global__ void k_off(const float* __restrict__ x, const short* __restrict__ w2h,
                      const short* __restrict__ w2l, const float* __restrict__ cst,
                      const float* __restrict__ bq, const short* __restrict__ wbf,
                      float* __restrict__ P, short* __restrict__ x_bf,
                      short* __restrict__ q_bf) {
    __shared__ __align__(16) char smem[34816];
    float* stageF = (float*)smem;                 // 64x132 fp32 (P) = 33792 B
    short* stageS = (short*)smem;                 // 128x136 bf16 (q) = 34816 B
    const int t = threadIdx.x;
    const int w = t >> 6, l = t & 63, l15 = l & 15, quad = l >> 4;
    const int p0 = blockIdx.x * 128;
    const int b = p0 >> 14, pix0 = p0 & (IMG - 1);
    const int h = pix0 >> 7;                      // image row of this block

    floatx4 accP[2][4];
    floatx4 accQ[2][8];
#pragma unroll
    for (int im = 0; im < 2; ++im) {
#pragma unroll
        for (int in = 0; in < 4; ++in) accP[im][in] = (floatx4){0.f, 0.f, 0.f, 0.f};
#pragma unroll
        for (int in = 0; in < 8; ++in) accQ[im][in] = (floatx4){0.f, 0.f, 0.f, 0.f};
    }

    const float* xb = x + (size_t)p0 * 128;
    short* xbb = x_bf + (size_t)p0 * 128;

#pragma unroll
    for (int kc = 0; kc < 128; kc += 32) {
        short8 ah[2], al[2];
#pragma unroll
        for (int im = 0; im < 2; ++im) {
            int row = w * 32 + im * 16 + l15;
            const float* src = xb + row * 128 + kc + quad * 8;
            float4 f0 = ld4(src), f1 = ld4(src + 4);
            float fv[8] = {f0.x, f0.y, f0.z, f0.w, f1.x, f1.y, f1.z, f1.w};
            short8 h8, l8;
#pragma unroll
            for (int r = 0; r < 8; ++r) {
                short hh = f2bf(fv[r]);
                h8[r] = hh;
                l8[r] = f2bf(fv[r] - bf2f(hh));
            }
            ah[im] = h8; al[im] = l8;
            *reinterpret_cast<short8*>(xbb + row * 128 + kc + quad * 8) = h8;
        }
        short8 bh[4], bl[4], bqf[8];
#pragma unroll
        for (int in = 0; in < 4; ++in) {
            int o = in * 16 + l15;
            bh[in] = *reinterpret_cast<const short8*>(w2h + o * 128 + kc + quad * 8);
            bl[in] = *reinterpret_cast<const short8*>(w2l + o * 128 + kc + quad * 8);
        }
#pragma unroll
        for (int in = 0; in < 8; ++in)
            bqf[in] = *reinterpret_cast<const short8*>(
                wbf + (in * 16 + l15) * 128 + kc + quad * 8);
#pragma unroll
        for (int im = 0; im < 2; ++im) {
#pragma unroll
            for (int in = 0; in < 4; ++in) {
                accP[im][in] = __builtin_amdgcn_mfma_f32_16x16x32_bf16(
                    ah[im], bh[in], accP[im][in], 0, 0, 0);
                accP[im][in] = __builtin_amdgcn_mfma_f32_16x16x32_bf16(
                    ah[im], bl[in], accP[im][in], 0, 0, 0);
                accP[im][in] = __builtin_amdgcn_mfma_f32_16x16x32_bf16(
                    al[im], bh[in], accP[im][in], 0, 0, 0);
            }
#pragma unroll
            for (int in = 0; in < 8; ++in)
                accQ[im][in] = __builtin_amdgcn_mfma_f32_16x16x32_bf16(
                    ah[im], bqf[in], accQ[im][in], 0, 0, 0);
        }
    }
    // ---- stage P tile (o 0..63 x px 0..127) then coalesced write of o<50 ----
#pragma unroll
    for (int im = 0; im < 2; ++im)
#pragma unroll
        for (int in = 0; in < 4; ++in) {
            int o = in * 16 + l15;
            int row0 = w * 32 + im * 16 + quad * 4;
            *reinterpret_cast<float4*>(&stageF[o * 132 + row0]) =
                make_float4(accP[im][in][0], accP[im][in][1],
                            accP[im][in][2], accP[im][in][3]);
        }
    __syncthreads();
    for (int id = t; id < 50 * 32; id += 256) {
        int o = id >> 5, px4 = (id & 31) * 4;
        float c = cst[o];
        float4 v = *reinterpret_cast<float4*>(&stageF[o * 132 + px4]);
        v.x += c; v.y += c; v.z += c; v.w += c;
        *reinterpret_cast<float4*>(P + ((size_t)(b * 50 + o)) * IMG + pix0 + px4) = v;
    }
    __syncthreads();                              // stageF reads done
    // ---- stage q bf16 (o 0..127 x px 0..127) ----
#pragma unroll
    for (int in = 0; in < 8; ++in) {
        int o = in * 16 + l15;
        float bb = bq[o];
#pragma unroll
        for (int im = 0; im < 2; ++im) {
            int row0 = w * 32 + im * 16 + quad * 4;
            short4v s = {f2bf(accQ[im][in][0] + bb), f2bf(accQ[im][in][1] + bb),
                         f2bf(accQ[im][in][2] + bb), f2bf(accQ[im][in][3] + bb)};
            *reinterpret_cast<short4v*>(&stageS[o * 136 + row0]) = s;
        }
    }
    __syncthreads();
    // coalesced q write
    for (int id = t; id < 2048; id += 256) {
        int o = id >> 4, seg = id & 15;
        *reinterpret_cast<short8*>(
            q_bf + ((size_t)(b * 128 + o)) * IMG + h * 128 + seg * 8)
            = *reinterpret_cast<const short8*>(&stageS[o * 136 + seg * 8]);
    }
}

// ---------------------------------------------------------------------------
// Kernel 3 (R19): FUSED per (b,h) row, 256 threads, 4 barriers, per-wave
// dataflow end-to-end:
//   A: per-wave P-halo load (cols w*32-4..+36; halo float4s duplicate-written
//      identically by neighbor waves - benign) -> per-wave conv+tanh (own
//      cols, bit-identical tap order) -> B2 (rowsP dead / offs ready).
//   B: per-wave gather (rows w*32..+31) -> xsT (no barrier).
//   C: per-wave k GEMM -> stage k->stg -> per-wave v GEMM (reuse acc) -> B3
//      -> stage v->xsT + k write -> B4 -> per-wave vw GEMM (reuse acc) ->
//      stage vw->stg -> B5 -> vw write.
// LDS: stg/rowsP 34816 + xsT 34816 + offs 1024 = 70656 B (2 blocks/CU).
// ---------------------------------------------------------------------------
__launch_bounds__(256, 2)
__global__ void k_fused3(const float* __restrict__ P, const float* __restrict__ b_eff,
                         const short* __restrict__ x_bf, const short* __restrict__ wbf,
                         const float* __restrict__ bk, const float* __restrict__ bv,
                         const float* __restrict__ rel,
                         short* __restrict__ k_bf, short* __restrict__ v_bf) {
    __shared__ __align__(16) char smem[70656];
    float* rowsP  = (float*)smem;                // 27200 B (phase A only)
    short* stg    = (short*)smem;                // 34816 B stage (aliases rowsP)
    short* xsT    = (short*)(smem + 34816);      // 34816 B
    float* offs_l = (float*)(smem + 69632);      // 1024 B

    const int t = threadIdx.x;
    const int w = t >> 6, l = t & 63, l15 = l & 15, quad = l >> 4;
    const int bh = blockIdx.x;
    const int b = bh >> 7, h = bh & 127;

    // ---- Phase A: per-wave P halo load (50 planes x 10 float4, own cols) ----
    {
        const int c0base = w * 32 - 4;
        for (int id = l; id < 500; id += 64) {
            int o = id / 10, i = id - (id / 10) * 10;
            int c0 = c0base + i * 4;
            int di = (o % 25) / 5;
            int r = h + di - 2;
            int rc = min(max(r, 0), 127);
            int cc = min(max(c0, 0), 124);
            float4 v = ld4(P + ((size_t)(b * 50 + o)) * IMG + rc * 128 + cc);
            float m = (r >= 0 && r < 128 && c0 >= 0 && c0 <= 124) ? 1.f : 0.f;
            v.x *= m; v.y *= m; v.z *= m; v.w *= m;
            *reinterpret_cast<float4*>(&rowsP[o * 136 + 4 + c0]) = v;
        }
    }
    // ---- per-wave conv + tanh (reads own-loaded cols; no barrier) ----
    {
        int px = w * 32 + (l & 31);
        int ch = l >> 5;
        float acc = 0.f;
#pragma unroll
        for (int di = 0; di < 5; ++di)
#pragma unroll
            for (int dj = 0; dj < 5; ++dj)
                acc += rowsP[(ch * 25 + di * 5 + dj) * 136 + px + dj + 2];
        offs_l[ch * 128 + px] = tanhf(acc + b_eff[ch]) * 5.0f;
    }
    __syncthreads();                             // B2: all convs done, rowsP dead

    // ---- Phase B: per-wave branch-free gather -> xsT (NO barrier) ----
    {
        const short* xbase = x_bf + (size_t)b * IMG * 128;
#pragma unroll
        for (int it = 0; it < 8; ++it) {
            int local = l + it * 64;             // 0..511 within wave
            int px = w * 32 + (local >> 4);      // wave's own rows
            int c8 = local & 15;
            float ox = offs_l[px];
            float oy = offs_l[128 + px];
            float xg = ((float)px + ox) * (128.0f / 127.0f) - 0.5f;
            float yg = ((float)h  + oy) * (128.0f / 127.0f) - 0.5f;
            float x0f = floorf(xg), y0f = floorf(yg);
            float fx = xg - x0f, fy = yg - y0f;
            int x0 = (int)x0f, y0 = (int)y0f;
            float s[8];
#pragma unroll
            for (int r = 0; r < 8; ++r) s[r] = 0.f;
#pragma unroll
            for (int tap = 0; tap < 4; ++tap) {
                int xi = x0 + (tap & 1), yi = y0 + (tap >> 1);
                float wgt = ((tap & 1) ? fx : 1.f - fx) * ((tap >> 1) ? fy : 1.f - fy);
                wgt = (xi >= 0 && xi < 128 && yi >= 0 && yi < 128) ? wgt : 0.f;
                int xc = min(max(xi, 0), 127), yc = min(max(yi, 0), 127);
                short8 v = *reinterpret_cast<const short8*>(
                    xbase + ((size_t)(yc * 128 + xc)) * 128 + c8 * 8);
#pragma unroll
                for (int r = 0; r < 8; ++r) s[r] = fmaf(wgt, bf2f(v[r]), s[r]);
            }
            short8 o;
#pragma unroll
            for (int r = 0; r < 8; ++r) o[r] = f2bf(s[r]);
            *reinterpret_cast<short8*>(&xsT[px * 136 + c8 * 8]) = o;
        }
    }

    floatx4 acc[2][8];

    // ---- per-wave k GEMM (A-rows = wave's gathered rows) ----
#pragma unroll
    for (int im = 0; im < 2; ++im)
#pragma unroll
        for (int in = 0; in < 8; ++in) acc[im][in] = (floatx4){0.f, 0.f, 0.f, 0.f};
#pragma unroll
    for (int kc = 0; kc < 128; kc += 32) {
        short8 af[2], bfr[8];
#pragma unroll
        for (int im = 0; im < 2; ++im)
            af[im] = *reinterpret_cast<const short8*>(
                &xsT[(w * 32 + im * 16 + l15) * 136 + kc + quad * 8]);
#pragma unroll
        for (int in = 0; in < 8; ++in)
            bfr[in] = *reinterpret_cast<const short8*>(
                wbf + 16384 + (in * 16 + l15) * 128 + kc + quad * 8);
#pragma unroll
        for (int im = 0; im < 2; ++im)
#pragma unroll
            for (int in = 0; in < 8; ++in)
                acc[im][in] = __builtin_amdgcn_mfma_f32_16x16x32_bf16(
                    af[im], bfr[in], acc[im][in], 0, 0, 0);
    }
    // stage k -> stg (per-wave columns; rowsP dead post-B2; no readers yet)
#pragma unroll
    for (int in = 0; in < 8; ++in) {
        int o = in * 16 + l15;
        float bbk = bk[o];
#pragma unroll
        for (int im = 0; im < 2; ++im) {
            int row0 = w * 32 + im * 16 + quad * 4;
            short4v sk = {f2bf(acc[im][in][0] + bbk), f2bf(acc[im][in][1] + bbk),
                          f2bf(acc[im][in][2] + bbk), f2bf(acc[im][in][3] + bbk)};
            *reinterpret_cast<short4v*>(&stg[o * 136 + row0]) = sk;
        }
    }

    // ---- per-wave v GEMM (reuse acc) ----
#pragma unroll
    for (int im = 0; im < 2; ++im)
#pragma unroll
        for (int in = 0; in < 8; ++in) acc[im][in] = (floatx4){0.f, 0.f, 0.f, 0.f};
#pragma unroll
    for (int kc = 0; kc < 128; kc += 32) {
        short8 af[2], bfr[8];
#pragma unroll
        for (int im = 0; im < 2; ++im)
            af[im] = *reinterpret_cast<const short8*>(
                &xsT[(w * 32 + im * 16 + l15) * 136 + kc + quad * 8]);
#pragma unroll
        for (int in = 0; in < 8; ++in)
            bfr[in] = *reinterpret_cast<const short8*>(
                wbf + 32768 + (in * 16 + l15) * 128 + kc + quad * 8);
#pragma unroll
        for (int im = 0; im < 2; ++im)
#pragma unroll
            for (int in = 0; in < 8; ++in)
                acc[im][in] = __builtin_amdgcn_mfma_f32_16x16x32_bf16(
                    af[im], bfr[in], acc[im][in], 0, 0, 0);
    }
    __syncthreads();                             // B3: all gather reads + k staged
    // stage biased v -> xsT (overwrites gathered data, safe after B3)
#pragma unroll
    for (int in = 0; in < 8; ++in) {
        int o = in * 16 + l15;
        float bbv = bv[o] + rel[o * 128 + h];
#pragma unroll
        for (int im = 0; im < 2; ++im) {
            int row0 = w * 32 + im * 16 + quad * 4;
            short4v sv = {f2bf(acc[im][in][0] + bbv), f2bf(acc[im][in][1] + bbv),
                          f2bf(acc[im][in][2] + bbv), f2bf(acc[im][in][3] + bbv)};
            *reinterpret_cast<short4v*>(&xsT[o * 136 + row0]) = sv;
        }
    }
    // coalesced k write (stg complete as of B3)
    for (int id = t; id < 2048; id += 256) {
        int o = id >> 4, seg = id & 15;
        *reinterpret_cast<short8*>(
            k_bf + ((size_t)(b * 128 + o)) * IMG + h * 128 + seg * 8)
            = *reinterpret_cast<const short8*>(&stg[o * 136 + seg * 8]);
    }
    __syncthreads();                             // B4: v staged; k-write stg reads done

    // ---- per-wave vw = v·Wo^T GEMM (reuse acc): D[o' rows w*32..+31][plane] ----
    {
        const short* WoB = wbf + 49152;
#pragma unroll
        for (int im = 0; im < 2; ++im)
#pragma unroll
            for (int in = 0; in < 8; ++in) acc[im][in] = (floatx4){0.f, 0.f, 0.f, 0.f};
#pragma unroll
        for (int kc = 0; kc < 128; kc += 32) {
            short8 af[2], bfr[8];
#pragma unroll
            for (int im = 0; im < 2; ++im)
                af[im] = *reinterpret_cast<const short8*>(
                    WoB + (w * 32 + im * 16 + l15) * 128 + kc + quad * 8);
#pragma unroll
            for (int in = 0; in < 8; ++in)
                bfr[in] = *reinterpret_cast<const short8*>(
                    &xsT[(in * 16 + l15) * 136 + kc + quad * 8]);
#pragma unroll
            for (int im = 0; im < 2; ++im)
#pragma unroll
                for (int in = 0; in < 8; ++in)
                    acc[im][in] = __builtin_amdgcn_mfma_f32_16x16x32_bf16(
                        af[im], bfr[in], acc[im][in], 0, 0, 0);
        }
        // stage vw -> stg (per-wave cols; stg's last reads finished before B4)
#pragma unroll
        for (int in = 0; in < 8; ++in) {
            int plane = in * 16 + l15;
#pragma unroll
            for (int im = 0; im < 2; ++im) {
                int row0 = w * 32 + im * 16 + quad * 4;    // o' base
                short4v s = {f2bf(acc[im][in][0]), f2bf(acc[im][in][1]),
                             f2bf(acc[im][in][2]), f2bf(acc[im][in][3])};
                *reinterpret_cast<short4v*>(&stg[plane * 136 + row0]) = s;
            }
        }
    }
    __syncthreads();                             // B5
    // coalesced vw write into v_bf
    for (int id = t; id < 2048; id += 256) {
        int o = id >> 4, seg = id & 15;
        *reinterpret_cast<short8*>(
            v_bf + ((size_t)(b * 128 + o)) * IMG + h * 128 + seg * 8)
            = *reinterpret_cast<const short8*>(&stg[o * 136 + seg * 8]);
    }
}

// ---------------------------------------------------------------------------
// Kernel 4 (R19): MFMA attention, 2 phases, 4 barriers (merged softmax).
// Phase 1: S=q·kT; each nh-half computes (m_half, sum e^(x-m_half)) BEFORE
// the barrier; ONE barrier; per-row rescale f=e^((m_half-mg)s)/s_g.
// Phase 2: Y = P·vw + bo (Wo pre-folded into vw). b64-packed vw->vT
// transpose; Y staged fp32 in LDS -> coalesced float4 stores.
// LDS: Pb 34816 + vT 34816 + redm 1024 + reds 1024 = 71680 B (2 blocks/CU).
// ---------------------------------------------------------------------------
__launch_bounds__(256, 2)
__global__ void k_attn3(const short* __restrict__ q_bf, const short* __restrict__ k_bf,
                        const short* __restrict__ v_bf,
                        const float* __restrict__ bo, float* __restrict__ outp) {
    __shared__ __align__(16) char smem[71680];
    short* Pb   = (short*)smem;                  // 34816 B: P bf16
    short* vT   = (short*)(smem + 34816);        // 34816 B: vw^T swizzled
    float* Ystg = (float*)smem;                  // 128x132 fp32 = 67584 B (epilogue)
    float* redm = (float*)(smem + 69632);        // 512 B x2
    float* reds = (float*)(smem + 70656);        // 512 B x2

    const int t = threadIdx.x;
    const int w = t >> 6, l = t & 63, l15 = l & 15, quad = l >> 4;
    const int mh = w >> 1, nh = w & 1;
    const size_t hb = (size_t)blockIdx.x * IMG;
    const short* qp = q_bf + hb;
    const short* kp = k_bf + hb;
    const short* vp = v_bf + hb;

    // ---- vw -> vT transpose (b64 writes, swizzled): 512 items, 2/thread ----
    for (int id = t; id < 512; id += 256) {
        int j4 = id >> 4, seg = id & 15;             // j-block of 4, d-block of 8
        const short* src = vp + (j4 * 4) * 128 + seg * 8;
        short8 v0 = *reinterpret_cast<const short8*>(src);
        short8 v1 = *reinterpret_cast<const short8*>(src + 128);
        short8 v2 = *reinterpret_cast<const short8*>(src + 256);
        short8 v3 = *reinterpret_cast<const short8*>(src + 384);
        int phys = (((j4 >> 1) ^ seg) & 15) * 8 + (j4 & 1) * 4;
#pragma unroll
        for (int r = 0; r < 8; ++r) {
            short4v wv = {v0[r], v1[r], v2[r], v3[r]};
            *reinterpret_cast<short4v*>(&vT[(seg * 8 + r) * 136 + phys]) = wv;
        }
    }

    floatx4 acc[4][4];
#pragma unroll
    for (int im = 0; im < 4; ++im)
#pragma unroll
        for (int in = 0; in < 4; ++in)
            acc[im][in] = (floatx4){0.f, 0.f, 0.f, 0.f};

    // ---- Phase 1: S = q·kT (direct-global frags) ----
#pragma unroll
    for (int kc = 0; kc < 128; kc += 32) {
        short8 af[4], bf_[4];
#pragma unroll
        for (int im = 0; im < 4; ++im)
            af[im] = *reinterpret_cast<const short8*>(
                qp + (mh * 64 + im * 16 + l15) * 128 + kc + quad * 8);
#pragma unroll
        for (int in = 0; in < 4; ++in)
            bf_[in] = *reinterpret_cast<const short8*>(
                kp + (nh * 64 + in * 16 + l15) * 128 + kc + quad * 8);
#pragma unroll
        for (int im = 0; im < 4; ++im)
#pragma unroll
            for (int in = 0; in < 4; ++in)
                acc[im][in] = __builtin_amdgcn_mfma_f32_16x16x32_bf16(
                    af[im], bf_[in], acc[im][in], 0, 0, 0);
    }

    const float scale = 0.08838834764831845f;
    // half-max over this nh-half's 64 cols
    float mloc[4][4];
#pragma unroll
    for (int im = 0; im < 4; ++im)
#pragma unroll
        for (int r = 0; r < 4; ++r) {
            float m = acc[im][0][r];
#pragma unroll
            for (int in = 1; in < 4; ++in) m = fmaxf(m, acc[im][in][r]);
            mloc[im][r] = m;
        }
#pragma unroll
    for (int mask = 1; mask < 16; mask <<= 1)
#pragma unroll
        for (int im = 0; im < 4; ++im)
#pragma unroll
            for (int r = 0; r < 4; ++r)
                mloc[im][r] = fmaxf(mloc[im][r], __shfl_xor(mloc[im][r], mask, 64));
    if (l15 == 0) {
#pragma unroll
        for (int im = 0; im < 4; ++im)
#pragma unroll
            for (int r = 0; r < 4; ++r)
                redm[nh * 128 + mh * 64 + im * 16 + quad * 4 + r] = mloc[im][r];
    }
    // exp relative to OWN half-max + half-sum (pre-barrier)
    float sloc[4][4];
#pragma unroll
    for (int im = 0; im < 4; ++im)
#pragma unroll
        for (int r = 0; r < 4; ++r) {
            float m = mloc[im][r];
            float ss = 0.f;
#pragma unroll
            for (int in = 0; in < 4; ++in) {
                float e = __expf((acc[im][in][r] - m) * scale);
                acc[im][in][r] = e;
                ss += e;
            }
            sloc[im][r] = ss;
        }
#pragma unroll
    for (int mask = 1; mask < 16; mask <<= 1)
#pragma unroll
        for (int im = 0; im < 4; ++im)
#pragma unroll
            for (int r = 0; r < 4; ++r)
                sloc[im][r] += __shfl_xor(sloc[im][r], mask, 64);
    if (l15 == 0) {
#pragma unroll
        for (int im = 0; im < 4; ++im)
#pragma unroll
            for (int r = 0; r < 4; ++r)
                reds[nh * 128 + mh * 64 + im * 16 + quad * 4 + r] = sloc[im][r];
    }
    __syncthreads();                             // SINGLE softmax barrier (covers vT too)
#pragma unroll
    for (int im = 0; im < 4; ++im)
#pragma unroll
        for (int r = 0; r < 4; ++r) {
            int row = mh * 64 + im * 16 + quad * 4 + r;
            float m0 = redm[row], m1 = redm[128 + row];
            float mg = fmaxf(m0, m1);
            float sg = reds[row] * __expf((m0 - mg) * scale) +
                       reds[128 + row] * __expf((m1 - mg) * scale);
            float f = __expf((mloc[im][r] - mg) * scale) / sg;
#pragma unroll
            for (int in = 0; in < 4; ++in) {
                int col = nh * 64 + in * 16 + l15;
                Pb[row * 136 + col] = f2bf(acc[im][in][r] * f);
            }
        }
    __syncthreads();                             // Pb ready

    // ---- Phase 2: Y = P·vw (A=Pb, B=vT swizzled) + bo ----
    float bb[4];
#pragma unroll
    for (int in = 0; in < 4; ++in) bb[in] = bo[nh * 64 + in * 16 + l15];
#pragma unroll
    for (int im = 0; im < 4; ++im)
#pragma unroll
        for (int in = 0; in < 4; ++in)
            acc[im][in] = (floatx4){0.f, 0.f, 0.f, 0.f};
#pragma unroll
    for (int kc = 0; kc < 128; kc += 32) {
        short8 af[4], bf_[4];
#pragma unroll
        for (int im = 0; im < 4; ++im)
            af[im] = *reinterpret_cast<const short8*>(
                &Pb[(mh * 64 + im * 16 + l15) * 136 + kc + quad * 8]);
#pragma unroll
        for (int in = 0; in < 4; ++in) {
            int dRow = nh * 64 + in * 16 + l15;
            int cphys = (((kc >> 3) + quad) ^ (dRow >> 3)) & 15;
            bf_[in] = *reinterpret_cast<const short8*>(
                &vT[dRow * 136 + cphys * 8]);
        }
#pragma unroll
        for (int im = 0; im < 4; ++im)
#pragma unroll
            for (int in = 0; in < 4; ++in)
                acc[im][in] = __builtin_amdgcn_mfma_f32_16x16x32_bf16(
                    af[im], bf_[in], acc[im][in], 0, 0, 0);
    }
    __syncthreads();                             // Pb/vT reads done; Ystg aliases
#pragma unroll
    for (int im = 0; im < 4; ++im)
#pragma unroll
        for (int in = 0; in < 4; ++in) {
            int col = nh * 64 + in * 16 + l15;
#pragma unroll
            for (int r = 0; r < 4; ++r) {
                int row = mh * 64 + im * 16 + quad * 4 + r;
                Ystg[row * 132 + col] = acc[im][in][r] + bb[in];
            }
        }
    __syncthreads();
    // coalesced Y write: 4096 float4, 16/thread
    for (int id = t; id < 4096; id += 256) {
        int row = id >> 5, c4 = (id & 31) * 4;
        *reinterpret_cast<float4*>(outp + hb + (size_t)row * 128 + c4) =
            *reinterpret_cast<const float4*>(&Ystg[row * 132 + c4]);
    }
}

// ---------------------------------------------------------------------------
extern "C" void kernel_launch(void* const* d_in, const int* in_sizes, int n_in,
                              void* d_out, int out_size, void* d_ws, size_t ws_size,
                              hipStream_t stream) {
    const float* x   = (const float*)d_in[0];
    const float* Wq  = (const float*)d_in[2];
    const float* bq  = (const float*)d_in[3];
    const float* Wk  = (const float*)d_in[4];
    const float* bk  = (const float*)d_in[5];
    const float* Wv  = (const float*)d_in[6];
    const float* bv  = (const float*)d_in[7];
    const float* Wo  = (const float*)d_in[8];
    const float* bo  = (const float*)d_in[9];
    const float* Wc1 = (const float*)d_in[10];
    const float* bc1 = (const float*)d_in[11];
    const float* Wc2 = (const float*)d_in[12];
    const float* rel = (const float*)d_in[13];

    char* wsb = (char*)d_ws;
    short* q_bf  = (short*)(wsb);                       // 16 MB
    short* k_bf  = (short*)(wsb + 1ull * 16777216);
    short* v_bf  = (short*)(wsb + 2ull * 16777216);
    short* x_bf  = (short*)(wsb + 3ull * 16777216);
    float* P     = (float*)(wsb + 4ull * 16777216);     // 13.1 MB
    float* W2    = (float*)(wsb + 4ull * 16777216 + 13107200);
    float* cst   = W2 + 6400;
    float* b_eff = cst + 64;
    short* wbf   = (short*)(b_eff + 16);                // 4 x 16384 bf16
    short* w2h   = wbf + 65536;                         // 64x128 bf16 (hi)
    short* w2l   = w2h + 8192;                          // 64x128 bf16 (lo)
    float* outp  = (float*)d_out;

    hipLaunchKernelGGL(k_wprep,  dim3(82),   dim3(256), 0, stream, Wc1, Wc2, bc1, Wq, bq,
                       Wk, Wv, Wo, W2, cst, b_eff, wbf, w2h, w2l);
    hipLaunchKernelGGL(k_off,    dim3(512),  dim3(256), 0, stream, x, w2h, w2l, cst,
                       bq, wbf, P, x_bf, q_bf);
    hipLaunchKernelGGL(k_fused3, dim3(512),  dim3(256), 0, stream, P, b_eff, x_bf, wbf,
                       bk, bv, rel, k_bf, v_bf);
    hipLaunchKernelGGL(k_attn3,  dim3(512),  dim3(256), 0, stream, q_bf, k_bf, v_bf,
                       bo, outp);
}